// Round 3
// baseline (535.135 us; speedup 1.0000x reference)
//
#include <hip/hip_runtime.h>

// OctreeDWConvBn: out[n,c] = BN_c( sum_k data[neigh[n,k],c] * weight[k,c] )
// N=131072, C=192, K=27. fp32 in/out; gathered operand staged as bf16.
// R3: 4-channel-per-lane gather (uint2), LDS-staged weights+indices,
//     bf16 conv intermediate to cut the BN-apply round-trip.

static constexpr int NN = 131072;   // nodes
static constexpr int CC = 192;      // channels
static constexpr int KK = 27;       // stencil taps
static constexpr int NB = 32;       // nodes per block
static constexpr float BN_EPS = 1e-5f;

__device__ __forceinline__ unsigned short f2bf_rne(float x) {
    unsigned u = __float_as_uint(x);
    return (unsigned short)((u + 0x7FFFu + ((u >> 16) & 1u)) >> 16);
}
__device__ __forceinline__ unsigned pack2bf(float a, float b) {
    return (unsigned)f2bf_rne(a) | ((unsigned)f2bf_rne(b) << 16);
}

// ---------------------------------------------------------------------------
// Kernel 0: fp32 -> bf16 staging of `data`.
// ---------------------------------------------------------------------------
__global__ __launch_bounds__(256) void cvt_bf16(
    const float* __restrict__ src, unsigned short* __restrict__ dst)
{
    const int i = blockIdx.x * 256 + threadIdx.x;     // float4 index
    const float4 v = reinterpret_cast<const float4*>(src)[i];
    ushort4 o;
    o.x = f2bf_rne(v.x); o.y = f2bf_rne(v.y);
    o.z = f2bf_rne(v.z); o.w = f2bf_rne(v.w);
    reinterpret_cast<ushort4*>(dst)[i] = o;
}

// ---------------------------------------------------------------------------
// Kernel 1: depthwise conv, 4 channels/lane via uint2 gather.
// Block = 192 threads: g = t/48 selects one of 4 concurrent nodes,
// q = t%48 selects the channel quad. 8 serial node-steps (NB=32).
// Weights + per-block neighbor indices staged in LDS.
// BF_OUT: write bf16-packed conv to ws (else fp32 to out).
// ---------------------------------------------------------------------------
template<bool BF_OUT>
__global__ __launch_bounds__(192) void conv4(
    const unsigned short* __restrict__ data_bf,  // [NN, CC] bf16
    const int*   __restrict__ neigh,             // [NN, KK]
    const float* __restrict__ weight,            // [KK, CC]
    float*       __restrict__ out_f32,           // [NN, CC] (if !BF_OUT)
    uint2*       __restrict__ out_bf,            // [NN*48]  (if BF_OUT)
    float*       __restrict__ ch_sum,            // [CC]
    float*       __restrict__ ch_sumsq)          // [CC]
{
    __shared__ __align__(16) float lds_w[KK * CC];   // 20736 B
    __shared__ int   lds_idx[NB * KK];               // 3456 B
    __shared__ float lds_s[CC];                      // 768 B
    __shared__ float lds_q[CC];                      // 768 B

    const int t = threadIdx.x;
    const int g = t / 48;          // node subgroup 0..3
    const int q = t - g * 48;      // channel quad 0..47
    const int base = blockIdx.x * NB;

    // Stage weights (coalesced: 27 rows of 192 floats).
#pragma unroll
    for (int k = 0; k < KK; ++k) lds_w[k * CC + t] = weight[k * CC + t];
    // Stage this block's neighbor indices (NB*KK = 864 ints).
    for (int i = t; i < NB * KK; i += 192) lds_idx[i] = neigh[base * KK + i];
    lds_s[t] = 0.f; lds_q[t] = 0.f;
    __syncthreads();

    const unsigned short* dptr = data_bf + q * 4;   // channel offset in row

    float s0 = 0, s1 = 0, s2 = 0, s3 = 0;
    float q0 = 0, q1 = 0, q2 = 0, q3 = 0;

    for (int sstep = 0; sstep < NB / 4; ++sstep) {
        const int ln = sstep * 4 + g;               // local node
        float a0 = 0, a1 = 0, a2 = 0, a3 = 0;
#pragma unroll
        for (int k = 0; k < KK; ++k) {
            const int idx = lds_idx[ln * KK + k];   // LDS broadcast
            const uint2 u = *reinterpret_cast<const uint2*>(
                dptr + (size_t)idx * CC);
            const float4 w4 = *reinterpret_cast<const float4*>(
                &lds_w[k * CC + q * 4]);
            a0 = fmaf(__uint_as_float(u.x << 16),         w4.x, a0);
            a1 = fmaf(__uint_as_float(u.x & 0xFFFF0000u), w4.y, a1);
            a2 = fmaf(__uint_as_float(u.y << 16),         w4.z, a2);
            a3 = fmaf(__uint_as_float(u.y & 0xFFFF0000u), w4.w, a3);
        }
        const int node = base + ln;
        if (BF_OUT) {
            uint2 o; o.x = pack2bf(a0, a1); o.y = pack2bf(a2, a3);
            out_bf[node * 48 + q] = o;
        } else {
            float4 o = make_float4(a0, a1, a2, a3);
            reinterpret_cast<float4*>(out_f32)[node * 48 + q] = o;
        }
        s0 += a0; s1 += a1; s2 += a2; s3 += a3;
        q0 += a0 * a0; q1 += a1 * a1; q2 += a2 * a2; q3 += a3 * a3;
    }

    // Block-level stat reduction: 4 g-copies per channel -> LDS atomics.
    const int cb = q * 4;
    atomicAdd(&lds_s[cb + 0], s0); atomicAdd(&lds_s[cb + 1], s1);
    atomicAdd(&lds_s[cb + 2], s2); atomicAdd(&lds_s[cb + 3], s3);
    atomicAdd(&lds_q[cb + 0], q0); atomicAdd(&lds_q[cb + 1], q1);
    atomicAdd(&lds_q[cb + 2], q2); atomicAdd(&lds_q[cb + 3], q3);
    __syncthreads();
    // One global atomic per channel per block (block has exactly CC threads).
    atomicAdd(&ch_sum[t],   lds_s[t]);
    atomicAdd(&ch_sumsq[t], lds_q[t]);
}

// ---------------------------------------------------------------------------
// Fallback conv (fp32 gather, block-uniform indices) — used only if ws is
// too small for bf16 staging.
// ---------------------------------------------------------------------------
__global__ __launch_bounds__(CC) void conv_bn_partial_f32(
    const float* __restrict__ data,
    const int*   __restrict__ neigh,
    const float* __restrict__ weight,
    float*       __restrict__ conv_out,
    float*       __restrict__ ch_sum,
    float*       __restrict__ ch_sumsq)
{
    const int c = threadIdx.x;
    const int base = blockIdx.x * NB;
    float w[KK];
#pragma unroll
    for (int k = 0; k < KK; ++k) w[k] = weight[k * CC + c];
    float s = 0.f, ss = 0.f;
    for (int n = 0; n < NB; ++n) {
        const int node = base + n;
        const int* nrow = neigh + node * KK;
        float acc = 0.f;
#pragma unroll
        for (int k = 0; k < KK; ++k)
            acc = fmaf(data[nrow[k] * CC + c], w[k], acc);
        conv_out[node * CC + c] = acc;
        s += acc; ss += acc * acc;
    }
    atomicAdd(&ch_sum[c], s);
    atomicAdd(&ch_sumsq[c], ss);
}

// ---------------------------------------------------------------------------
// Kernel 2: fold channel sums into affine scale/bias.
// ---------------------------------------------------------------------------
__global__ __launch_bounds__(CC) void bn_finalize(
    const float* __restrict__ ch_sum, const float* __restrict__ ch_sumsq,
    const float* __restrict__ gamma,  const float* __restrict__ beta,
    float* __restrict__ scale, float* __restrict__ bias)
{
    const int c = threadIdx.x;
    const float inv_n = 1.0f / (float)NN;
    const float m  = ch_sum[c] * inv_n;
    const float v  = ch_sumsq[c] * inv_n - m * m;
    const float sc = gamma[c] * rsqrtf(v + BN_EPS);
    scale[c] = sc;
    bias[c]  = beta[c] - m * sc;
}

// ---------------------------------------------------------------------------
// Kernel 3a: normalize from bf16 intermediate -> fp32 out.
// ---------------------------------------------------------------------------
__global__ __launch_bounds__(256) void bn_apply_bf16(
    const uint2* __restrict__ conv_bf,
    const float* __restrict__ scale, const float* __restrict__ bias,
    float* __restrict__ out)
{
    const int i = blockIdx.x * 256 + threadIdx.x;   // uint2 / float4 index
    const int cb = (i % 48) * 4;
    const uint2 u = conv_bf[i];
    const float4 sc = *reinterpret_cast<const float4*>(scale + cb);
    const float4 bi = *reinterpret_cast<const float4*>(bias + cb);
    float4 v;
    v.x = fmaf(__uint_as_float(u.x << 16),         sc.x, bi.x);
    v.y = fmaf(__uint_as_float(u.x & 0xFFFF0000u), sc.y, bi.y);
    v.z = fmaf(__uint_as_float(u.y << 16),         sc.z, bi.z);
    v.w = fmaf(__uint_as_float(u.y & 0xFFFF0000u), sc.w, bi.w);
    reinterpret_cast<float4*>(out)[i] = v;
}

// ---------------------------------------------------------------------------
// Kernel 3b: in-place fp32 normalize (fallback tiers).
// ---------------------------------------------------------------------------
__global__ __launch_bounds__(256) void bn_apply(
    float* __restrict__ out,
    const float* __restrict__ scale, const float* __restrict__ bias)
{
    const int i = blockIdx.x * 256 + threadIdx.x;
    const int cb = (i % 48) * 4;
    float4 v = reinterpret_cast<float4*>(out)[i];
    const float4 sc = *reinterpret_cast<const float4*>(scale + cb);
    const float4 bi = *reinterpret_cast<const float4*>(bias + cb);
    v.x = fmaf(v.x, sc.x, bi.x); v.y = fmaf(v.y, sc.y, bi.y);
    v.z = fmaf(v.z, sc.z, bi.z); v.w = fmaf(v.w, sc.w, bi.w);
    reinterpret_cast<float4*>(out)[i] = v;
}

extern "C" void kernel_launch(void* const* d_in, const int* in_sizes, int n_in,
                              void* d_out, int out_size, void* d_ws, size_t ws_size,
                              hipStream_t stream) {
    const float* data   = (const float*)d_in[0];
    const int*   neigh  = (const int*)  d_in[1];
    const float* weight = (const float*)d_in[2];
    const float* gamma  = (const float*)d_in[3];
    const float* beta   = (const float*)d_in[4];
    float* out = (float*)d_out;

    // ws: stats (4096 B) | data_bf (50.3 MB) | conv_bf (50.3 MB)
    float* ch_sum   = (float*)d_ws;
    float* ch_sumsq = ch_sum + CC;
    float* scale    = ch_sumsq + CC;
    float* bias     = scale + CC;
    unsigned short* data_bf = (unsigned short*)((char*)d_ws + 4096);
    const size_t stage_bytes = (size_t)NN * CC * sizeof(unsigned short);
    uint2* conv_bf = (uint2*)((char*)d_ws + 4096 + stage_bytes);

    const size_t need_data = 4096 + stage_bytes;
    const size_t need_full = 4096 + 2 * stage_bytes;

    hipMemsetAsync(ch_sum, 0, 2 * CC * sizeof(float), stream);

    const int vec_grid = (NN * CC / 4) / 256;   // 24576

    if (ws_size >= need_full) {
        cvt_bf16<<<vec_grid, 256, 0, stream>>>(data, data_bf);
        conv4<true><<<NN / NB, 192, 0, stream>>>(
            data_bf, neigh, weight, nullptr, conv_bf, ch_sum, ch_sumsq);
        bn_finalize<<<1, CC, 0, stream>>>(ch_sum, ch_sumsq, gamma, beta,
                                          scale, bias);
        bn_apply_bf16<<<vec_grid, 256, 0, stream>>>(conv_bf, scale, bias, out);
    } else if (ws_size >= need_data) {
        cvt_bf16<<<vec_grid, 256, 0, stream>>>(data, data_bf);
        conv4<false><<<NN / NB, 192, 0, stream>>>(
            data_bf, neigh, weight, out, nullptr, ch_sum, ch_sumsq);
        bn_finalize<<<1, CC, 0, stream>>>(ch_sum, ch_sumsq, gamma, beta,
                                          scale, bias);
        bn_apply<<<vec_grid, 256, 0, stream>>>(out, scale, bias);
    } else {
        conv_bn_partial_f32<<<NN / NB, CC, 0, stream>>>(
            data, neigh, weight, out, ch_sum, ch_sumsq);
        bn_finalize<<<1, CC, 0, stream>>>(ch_sum, ch_sumsq, gamma, beta,
                                          scale, bias);
        bn_apply<<<vec_grid, 256, 0, stream>>>(out, scale, bias);
    }
}

// Round 4
// 412.663 us; speedup vs baseline: 1.2968x; 1.2968x over previous
//
#include <hip/hip_runtime.h>

// OctreeDWConvBn: out[n,c] = BN_c( sum_k data[neigh[n,k],c] * weight[k,c] )
// N=131072, C=192, K=27. fp32 in/out; gathered operand staged as bf16.
// R4: R2 gather shape (thread=channel, uniform indices) + max outstanding
//     loads (r[27] batch issue, weights in LDS, VGPR<=64 via launch_bounds)
//     + bf16 conv intermediate for a lighter BN-apply pass.

static constexpr int NN = 131072;   // nodes
static constexpr int CC = 192;      // channels
static constexpr int KK = 27;      // stencil taps
static constexpr int NB = 32;      // nodes per block (serial)
static constexpr float BN_EPS = 1e-5f;

__device__ __forceinline__ unsigned short f2bf_rne(float x) {
    unsigned u = __float_as_uint(x);
    return (unsigned short)((u + 0x7FFFu + ((u >> 16) & 1u)) >> 16);
}

// ---------------------------------------------------------------------------
// Kernel 0: fp32 -> bf16 staging of `data`.
// ---------------------------------------------------------------------------
__global__ __launch_bounds__(256) void cvt_bf16(
    const float* __restrict__ src, unsigned short* __restrict__ dst)
{
    const int i = blockIdx.x * 256 + threadIdx.x;     // float4 index
    const float4 v = reinterpret_cast<const float4*>(src)[i];
    ushort4 o;
    o.x = f2bf_rne(v.x); o.y = f2bf_rne(v.y);
    o.z = f2bf_rne(v.z); o.w = f2bf_rne(v.w);
    reinterpret_cast<ushort4*>(dst)[i] = o;
}

// ---------------------------------------------------------------------------
// Kernel 1 (R4): depthwise conv + per-block partial BN sums.
// Block = 192 threads (thread = channel). Per node: batch-issue all 27
// gather loads into r[27] (27 vmem in flight per wave), then FMA against
// LDS-held weights. Neighbor indices are block-uniform -> scalar loads.
// Conv result stored bf16 to ws; stats accumulated in fp32.
// ---------------------------------------------------------------------------
__global__ __launch_bounds__(192, 8) void conv_r4(
    const unsigned short* __restrict__ data_bf,   // [NN, CC] bf16 bits
    const int*   __restrict__ neigh,              // [NN, KK]
    const float* __restrict__ weight,             // [KK, CC]
    unsigned short* __restrict__ conv_bf,         // [NN, CC] bf16 bits (ws)
    float*       __restrict__ ch_sum,             // [CC]
    float*       __restrict__ ch_sumsq)           // [CC]
{
    __shared__ float lds_w[KK * CC];              // 20736 B

    const int c    = threadIdx.x;
    const int base = blockIdx.x * NB;

    // Stage weights in LDS (stride-1 across lanes: conflict-free).
#pragma unroll
    for (int k = 0; k < KK; ++k) lds_w[k * CC + c] = weight[k * CC + c];
    __syncthreads();

    float s = 0.f, ss = 0.f;

    for (int n = 0; n < NB; ++n) {
        const int node = base + n;                  // block-uniform
        const int* nrow = neigh + node * KK;        // uniform -> s_load

        // Batch-issue all 27 gathers: 27 global_load_ushort in flight.
        unsigned short r[KK];
#pragma unroll
        for (int k = 0; k < KK; ++k)
            r[k] = data_bf[(size_t)nrow[k] * CC + c];

        float acc = 0.f;
#pragma unroll
        for (int k = 0; k < KK; ++k)
            acc = fmaf(__uint_as_float((unsigned)r[k] << 16),
                       lds_w[k * CC + c], acc);

        conv_bf[(size_t)node * CC + c] = f2bf_rne(acc);  // 128 B/wave store
        s  += acc;
        ss += acc * acc;
    }

    // One global atomic per channel per block (192 = CC threads).
    atomicAdd(&ch_sum[c],   s);
    atomicAdd(&ch_sumsq[c], ss);
}

// ---------------------------------------------------------------------------
// Fallback conv (fp32 gather, fp32 out) — only if ws can't hold staging.
// ---------------------------------------------------------------------------
__global__ __launch_bounds__(CC) void conv_bn_partial_f32(
    const float* __restrict__ data,
    const int*   __restrict__ neigh,
    const float* __restrict__ weight,
    float*       __restrict__ conv_out,
    float*       __restrict__ ch_sum,
    float*       __restrict__ ch_sumsq)
{
    const int c = threadIdx.x;
    const int base = blockIdx.x * NB;
    float w[KK];
#pragma unroll
    for (int k = 0; k < KK; ++k) w[k] = weight[k * CC + c];
    float s = 0.f, ss = 0.f;
    for (int n = 0; n < NB; ++n) {
        const int node = base + n;
        const int* nrow = neigh + node * KK;
        float acc = 0.f;
#pragma unroll
        for (int k = 0; k < KK; ++k)
            acc = fmaf(data[nrow[k] * CC + c], w[k], acc);
        conv_out[node * CC + c] = acc;
        s += acc; ss += acc * acc;
    }
    atomicAdd(&ch_sum[c], s);
    atomicAdd(&ch_sumsq[c], ss);
}

// ---------------------------------------------------------------------------
// Kernel 2: fold channel sums into affine scale/bias.
// ---------------------------------------------------------------------------
__global__ __launch_bounds__(CC) void bn_finalize(
    const float* __restrict__ ch_sum, const float* __restrict__ ch_sumsq,
    const float* __restrict__ gamma,  const float* __restrict__ beta,
    float* __restrict__ scale, float* __restrict__ bias)
{
    const int c = threadIdx.x;
    const float inv_n = 1.0f / (float)NN;
    const float m  = ch_sum[c] * inv_n;
    const float v  = ch_sumsq[c] * inv_n - m * m;
    const float sc = gamma[c] * rsqrtf(v + BN_EPS);
    scale[c] = sc;
    bias[c]  = beta[c] - m * sc;
}

// ---------------------------------------------------------------------------
// Kernel 3a: normalize from bf16 intermediate -> fp32 out.
// ---------------------------------------------------------------------------
__global__ __launch_bounds__(256) void bn_apply_bf16(
    const uint2* __restrict__ conv_bf,
    const float* __restrict__ scale, const float* __restrict__ bias,
    float* __restrict__ out)
{
    const int i = blockIdx.x * 256 + threadIdx.x;   // uint2 / float4 index
    const int cb = (i % 48) * 4;
    const uint2 u = conv_bf[i];
    const float4 sc = *reinterpret_cast<const float4*>(scale + cb);
    const float4 bi = *reinterpret_cast<const float4*>(bias + cb);
    float4 v;
    v.x = fmaf(__uint_as_float(u.x << 16),         sc.x, bi.x);
    v.y = fmaf(__uint_as_float(u.x & 0xFFFF0000u), sc.y, bi.y);
    v.z = fmaf(__uint_as_float(u.y << 16),         sc.z, bi.z);
    v.w = fmaf(__uint_as_float(u.y & 0xFFFF0000u), sc.w, bi.w);
    reinterpret_cast<float4*>(out)[i] = v;
}

// ---------------------------------------------------------------------------
// Kernel 3b: in-place fp32 normalize (fallback tier).
// ---------------------------------------------------------------------------
__global__ __launch_bounds__(256) void bn_apply(
    float* __restrict__ out,
    const float* __restrict__ scale, const float* __restrict__ bias)
{
    const int i = blockIdx.x * 256 + threadIdx.x;
    const int cb = (i % 48) * 4;
    float4 v = reinterpret_cast<float4*>(out)[i];
    const float4 sc = *reinterpret_cast<const float4*>(scale + cb);
    const float4 bi = *reinterpret_cast<const float4*>(bias + cb);
    v.x = fmaf(v.x, sc.x, bi.x); v.y = fmaf(v.y, sc.y, bi.y);
    v.z = fmaf(v.z, sc.z, bi.z); v.w = fmaf(v.w, sc.w, bi.w);
    reinterpret_cast<float4*>(out)[i] = v;
}

extern "C" void kernel_launch(void* const* d_in, const int* in_sizes, int n_in,
                              void* d_out, int out_size, void* d_ws, size_t ws_size,
                              hipStream_t stream) {
    const float* data   = (const float*)d_in[0];
    const int*   neigh  = (const int*)  d_in[1];
    const float* weight = (const float*)d_in[2];
    const float* gamma  = (const float*)d_in[3];
    const float* beta   = (const float*)d_in[4];
    float* out = (float*)d_out;

    // ws: stats (4096 B) | data_bf (50.3 MB) | conv_bf (50.3 MB)
    float* ch_sum   = (float*)d_ws;
    float* ch_sumsq = ch_sum + CC;
    float* scale    = ch_sumsq + CC;
    float* bias     = scale + CC;
    unsigned short* data_bf = (unsigned short*)((char*)d_ws + 4096);
    const size_t stage_bytes = (size_t)NN * CC * sizeof(unsigned short);
    unsigned short* conv_bf =
        (unsigned short*)((char*)d_ws + 4096 + stage_bytes);

    const size_t need_full = 4096 + 2 * stage_bytes;

    hipMemsetAsync(ch_sum, 0, 2 * CC * sizeof(float), stream);

    const int vec_grid = (NN * CC / 4) / 256;   // 24576

    if (ws_size >= need_full) {
        cvt_bf16<<<vec_grid, 256, 0, stream>>>(data, data_bf);
        conv_r4<<<NN / NB, 192, 0, stream>>>(
            data_bf, neigh, weight, conv_bf, ch_sum, ch_sumsq);
        bn_finalize<<<1, CC, 0, stream>>>(ch_sum, ch_sumsq, gamma, beta,
                                          scale, bias);
        bn_apply_bf16<<<vec_grid, 256, 0, stream>>>(
            (const uint2*)conv_bf, scale, bias, out);
    } else {
        conv_bn_partial_f32<<<NN / NB, CC, 0, stream>>>(
            data, neigh, weight, out, ch_sum, ch_sumsq);
        bn_finalize<<<1, CC, 0, stream>>>(ch_sum, ch_sumsq, gamma, beta,
                                          scale, bias);
        bn_apply<<<vec_grid, 256, 0, stream>>>(out, scale, bias);
    }
}

// Round 5
// 406.698 us; speedup vs baseline: 1.3158x; 1.0147x over previous
//
#include <hip/hip_runtime.h>

// OctreeDWConvBn: out[n,c] = BN_c( sum_k data[neigh[n,k],c] * weight[k,c] )
// N=131072, C=192, K=27. fp32 in/out; gathered operand staged as bf16.
// R5: dispatch-count reduction. 3 kernels total:
//   1) cvt_zero  : fp32->bf16 staging + zero stat accumulators (no memset)
//   2) conv_r4   : unchanged from R4 (215 us, fabric-bound at ~3.4 TB/s)
//   3) bn_apply_fused : per-thread BN finalize + normalize (no bn_finalize)

static constexpr int NN = 131072;   // nodes
static constexpr int CC = 192;      // channels
static constexpr int KK = 27;       // stencil taps
static constexpr int NB = 32;       // nodes per block (serial)
static constexpr float BN_EPS = 1e-5f;

__device__ __forceinline__ unsigned short f2bf_rne(float x) {
    unsigned u = __float_as_uint(x);
    return (unsigned short)((u + 0x7FFFu + ((u >> 16) & 1u)) >> 16);
}

// ---------------------------------------------------------------------------
// Kernel 1: fp32 -> bf16 staging of `data`, plus zeroing the stat buffers
// (replaces the separate hipMemsetAsync dispatch).
// ---------------------------------------------------------------------------
__global__ __launch_bounds__(256) void cvt_zero(
    const float* __restrict__ src, unsigned short* __restrict__ dst,
    float* __restrict__ stats /* [2*CC] sum|sumsq */)
{
    if (blockIdx.x < 2 && threadIdx.x < CC)
        stats[blockIdx.x * CC + threadIdx.x] = 0.f;

    const int i = blockIdx.x * 256 + threadIdx.x;     // float4 index
    const float4 v = reinterpret_cast<const float4*>(src)[i];
    ushort4 o;
    o.x = f2bf_rne(v.x); o.y = f2bf_rne(v.y);
    o.z = f2bf_rne(v.z); o.w = f2bf_rne(v.w);
    reinterpret_cast<ushort4*>(dst)[i] = o;
}

// ---------------------------------------------------------------------------
// Kernel 2 (unchanged R4): depthwise conv + per-block partial BN sums.
// Block = 192 threads (thread = channel). Per node: batch-issue all 27
// gather loads into r[27], then FMA against LDS-held weights. Neighbor
// indices are block-uniform -> scalar loads. Conv result stored bf16.
// ---------------------------------------------------------------------------
__global__ __launch_bounds__(192, 8) void conv_r4(
    const unsigned short* __restrict__ data_bf,   // [NN, CC] bf16 bits
    const int*   __restrict__ neigh,              // [NN, KK]
    const float* __restrict__ weight,             // [KK, CC]
    unsigned short* __restrict__ conv_bf,         // [NN, CC] bf16 bits (ws)
    float*       __restrict__ ch_sum,             // [CC]
    float*       __restrict__ ch_sumsq)           // [CC]
{
    __shared__ float lds_w[KK * CC];              // 20736 B

    const int c    = threadIdx.x;
    const int base = blockIdx.x * NB;

#pragma unroll
    for (int k = 0; k < KK; ++k) lds_w[k * CC + c] = weight[k * CC + c];
    __syncthreads();

    float s = 0.f, ss = 0.f;

    for (int n = 0; n < NB; ++n) {
        const int node = base + n;                  // block-uniform
        const int* nrow = neigh + node * KK;        // uniform -> s_load

        unsigned short r[KK];
#pragma unroll
        for (int k = 0; k < KK; ++k)
            r[k] = data_bf[(size_t)nrow[k] * CC + c];

        float acc = 0.f;
#pragma unroll
        for (int k = 0; k < KK; ++k)
            acc = fmaf(__uint_as_float((unsigned)r[k] << 16),
                       lds_w[k * CC + c], acc);

        conv_bf[(size_t)node * CC + c] = f2bf_rne(acc);
        s  += acc;
        ss += acc * acc;
    }

    atomicAdd(&ch_sum[c],   s);
    atomicAdd(&ch_sumsq[c], ss);
}

// ---------------------------------------------------------------------------
// Kernel 3: fused BN finalize + normalize.
// Block = 192 threads: t = g*48 + q, q = fixed channel-quad (channels 4q..),
// g = node subgroup 0..3. Per-thread scale/bias computed ONCE from the
// channel stats (kernel-boundary coherence from conv's atomics), then
// grid-stride over node-groups: read uint2 (4 bf16), write float4.
// Wave = 512 B contiguous reads, 1 KiB contiguous writes.
// ---------------------------------------------------------------------------
__global__ __launch_bounds__(192) void bn_apply_fused(
    const uint2* __restrict__ conv_bf,   // [NN*48]
    const float* __restrict__ ch_sum,
    const float* __restrict__ ch_sumsq,
    const float* __restrict__ gamma,
    const float* __restrict__ beta,
    float* __restrict__ out)             // [NN, CC]
{
    const int t = threadIdx.x;
    const int g = t / 48;          // node subgroup 0..3
    const int q = t - g * 48;      // channel quad 0..47 (fixed per thread)
    const int cb = q * 4;

    const float inv_n = 1.0f / (float)NN;
    float4 sc, bi;
    {
        float m0 = ch_sum[cb + 0] * inv_n, m1 = ch_sum[cb + 1] * inv_n;
        float m2 = ch_sum[cb + 2] * inv_n, m3 = ch_sum[cb + 3] * inv_n;
        float v0 = ch_sumsq[cb + 0] * inv_n - m0 * m0;
        float v1 = ch_sumsq[cb + 1] * inv_n - m1 * m1;
        float v2 = ch_sumsq[cb + 2] * inv_n - m2 * m2;
        float v3 = ch_sumsq[cb + 3] * inv_n - m3 * m3;
        sc.x = gamma[cb + 0] * rsqrtf(v0 + BN_EPS);
        sc.y = gamma[cb + 1] * rsqrtf(v1 + BN_EPS);
        sc.z = gamma[cb + 2] * rsqrtf(v2 + BN_EPS);
        sc.w = gamma[cb + 3] * rsqrtf(v3 + BN_EPS);
        bi.x = beta[cb + 0] - m0 * sc.x;
        bi.y = beta[cb + 1] - m1 * sc.y;
        bi.z = beta[cb + 2] - m2 * sc.z;
        bi.w = beta[cb + 3] - m3 * sc.w;
    }

    // Grid-stride over groups of 4 nodes.
    for (int nb = blockIdx.x; nb < NN / 4; nb += gridDim.x) {
        const int node = nb * 4 + g;
        const int i = node * 48 + q;
        const uint2 u = conv_bf[i];
        float4 v;
        v.x = fmaf(__uint_as_float(u.x << 16),         sc.x, bi.x);
        v.y = fmaf(__uint_as_float(u.x & 0xFFFF0000u), sc.y, bi.y);
        v.z = fmaf(__uint_as_float(u.y << 16),         sc.z, bi.z);
        v.w = fmaf(__uint_as_float(u.y & 0xFFFF0000u), sc.w, bi.w);
        reinterpret_cast<float4*>(out)[i] = v;
    }
}

// ---------------------------------------------------------------------------
// Fallback tier (ws too small): fp32 conv + fused apply on fp32.
// ---------------------------------------------------------------------------
__global__ __launch_bounds__(CC) void conv_bn_partial_f32(
    const float* __restrict__ data,
    const int*   __restrict__ neigh,
    const float* __restrict__ weight,
    float*       __restrict__ conv_out,
    float*       __restrict__ ch_sum,
    float*       __restrict__ ch_sumsq)
{
    const int c = threadIdx.x;
    const int base = blockIdx.x * NB;
    if (blockIdx.x < 2 && c < CC) { /* no-op; stats zeroed host-side here */ }
    float w[KK];
#pragma unroll
    for (int k = 0; k < KK; ++k) w[k] = weight[k * CC + c];
    float s = 0.f, ss = 0.f;
    for (int n = 0; n < NB; ++n) {
        const int node = base + n;
        const int* nrow = neigh + node * KK;
        float acc = 0.f;
#pragma unroll
        for (int k = 0; k < KK; ++k)
            acc = fmaf(data[nrow[k] * CC + c], w[k], acc);
        conv_out[node * CC + c] = acc;
        s += acc; ss += acc * acc;
    }
    atomicAdd(&ch_sum[c], s);
    atomicAdd(&ch_sumsq[c], ss);
}

__global__ __launch_bounds__(192) void bn_apply_f32_fused(
    float* __restrict__ out,
    const float* __restrict__ ch_sum,
    const float* __restrict__ ch_sumsq,
    const float* __restrict__ gamma,
    const float* __restrict__ beta)
{
    const int t = threadIdx.x;
    const int g = t / 48;
    const int q = t - g * 48;
    const int cb = q * 4;
    const float inv_n = 1.0f / (float)NN;
    float4 sc, bi;
    float m0 = ch_sum[cb+0]*inv_n, m1 = ch_sum[cb+1]*inv_n;
    float m2 = ch_sum[cb+2]*inv_n, m3 = ch_sum[cb+3]*inv_n;
    sc.x = gamma[cb+0]*rsqrtf(ch_sumsq[cb+0]*inv_n - m0*m0 + BN_EPS);
    sc.y = gamma[cb+1]*rsqrtf(ch_sumsq[cb+1]*inv_n - m1*m1 + BN_EPS);
    sc.z = gamma[cb+2]*rsqrtf(ch_sumsq[cb+2]*inv_n - m2*m2 + BN_EPS);
    sc.w = gamma[cb+3]*rsqrtf(ch_sumsq[cb+3]*inv_n - m3*m3 + BN_EPS);
    bi.x = beta[cb+0] - m0*sc.x; bi.y = beta[cb+1] - m1*sc.y;
    bi.z = beta[cb+2] - m2*sc.z; bi.w = beta[cb+3] - m3*sc.w;
    for (int nb = blockIdx.x; nb < NN / 4; nb += gridDim.x) {
        const int i = (nb * 4 + g) * 48 + q;
        float4 v = reinterpret_cast<float4*>(out)[i];
        v.x = fmaf(v.x, sc.x, bi.x); v.y = fmaf(v.y, sc.y, bi.y);
        v.z = fmaf(v.z, sc.z, bi.z); v.w = fmaf(v.w, sc.w, bi.w);
        reinterpret_cast<float4*>(out)[i] = v;
    }
}

extern "C" void kernel_launch(void* const* d_in, const int* in_sizes, int n_in,
                              void* d_out, int out_size, void* d_ws, size_t ws_size,
                              hipStream_t stream) {
    const float* data   = (const float*)d_in[0];
    const int*   neigh  = (const int*)  d_in[1];
    const float* weight = (const float*)d_in[2];
    const float* gamma  = (const float*)d_in[3];
    const float* beta   = (const float*)d_in[4];
    float* out = (float*)d_out;

    // ws: stats 2*CC floats (padded to 4096 B) | data_bf 50.3 MB | conv_bf 50.3 MB
    float* stats    = (float*)d_ws;          // [0..191]=sum, [192..383]=sumsq
    float* ch_sum   = stats;
    float* ch_sumsq = stats + CC;
    unsigned short* data_bf = (unsigned short*)((char*)d_ws + 4096);
    const size_t stage_bytes = (size_t)NN * CC * sizeof(unsigned short);
    unsigned short* conv_bf =
        (unsigned short*)((char*)d_ws + 4096 + stage_bytes);

    const size_t need_full = 4096 + 2 * stage_bytes;
    const int vec_grid = (NN * CC / 4) / 256;   // 24576

    if (ws_size >= need_full) {
        cvt_zero<<<vec_grid, 256, 0, stream>>>(data, data_bf, stats);
        conv_r4<<<NN / NB, 192, 0, stream>>>(
            data_bf, neigh, weight, conv_bf, ch_sum, ch_sumsq);
        bn_apply_fused<<<8192, 192, 0, stream>>>(
            (const uint2*)conv_bf, ch_sum, ch_sumsq, gamma, beta, out);
    } else {
        hipMemsetAsync(stats, 0, 2 * CC * sizeof(float), stream);
        conv_bn_partial_f32<<<NN / NB, CC, 0, stream>>>(
            data, neigh, weight, out, ch_sum, ch_sumsq);
        bn_apply_f32_fused<<<8192, 192, 0, stream>>>(
            out, ch_sum, ch_sumsq, gamma, beta);
    }
}